// Round 18
// baseline (166.118 us; speedup 1.0000x reference)
//
#include <hip/hip_runtime.h>
#include <stdint.h>

typedef short short8 __attribute__((ext_vector_type(8)));
typedef short short4v __attribute__((ext_vector_type(4)));
typedef float f32x4 __attribute__((ext_vector_type(4)));
typedef float float4v __attribute__((ext_vector_type(4)));

__device__ inline float bf2f(short s) {
    union { unsigned u; float f; } c;
    c.u = ((unsigned)(unsigned short)s) << 16;
    return c.f;
}
__device__ inline short f2bf(float f) {
    union { float f; unsigned u; } c;
    c.f = f;
    unsigned u = c.u;
    unsigned r = (u + 0x7fffu + ((u >> 16) & 1u)) >> 16;
    return (short)r;
}

typedef const __attribute__((address_space(1))) char GChar;
typedef __attribute__((address_space(3))) char LChar;
__device__ __forceinline__ void gload_lds16(const void* g, void* l) {
    __builtin_amdgcn_global_load_lds((GChar*)g, (LChar*)l, 16, 0, 0);
}

template<int N> __device__ __forceinline__ void wait_vm() {
    if constexpr (N == 0)      asm volatile("s_waitcnt vmcnt(0)" ::: "memory");
    else if constexpr (N == 4) asm volatile("s_waitcnt vmcnt(4)" ::: "memory");
    else if constexpr (N == 6) asm volatile("s_waitcnt vmcnt(6)" ::: "memory");
    else static_assert(N == 0 || N == 4 || N == 6, "unsupported vmcnt");
}

__device__ __forceinline__ void wait_lgkm0() {
    asm volatile("s_waitcnt lgkmcnt(0)" ::: "memory");
}
__device__ __forceinline__ void wait_lgkm8() {
    asm volatile("s_waitcnt lgkmcnt(8)" ::: "memory");
}

__device__ __forceinline__ void phase_barrier() {
    __builtin_amdgcn_s_barrier();
    asm volatile("" ::: "memory");
}

// XCD-aware (x,y)-plane swizzle; requires gridDim.x*gridDim.y % 8 == 0.
__device__ __forceinline__ void swz_xy(int& bx, int& by) {
    int gx = gridDim.x;
    int nwg = gx * gridDim.y;
    int wg = by * gx + bx;
    int chunk = nwg >> 3;
    int swz = (wg & 7) * chunk + (wg >> 3);
    bx = swz % gx;
    by = swz / gx;
}

// ------- all-4 weight fp32 -> bf16 convert (wq scaled) + bias prep + zeroing -------
__global__ __launch_bounds__(256) void conv_w4(const float* __restrict__ w0, const float* __restrict__ w1,
                                               const float* __restrict__ w2, const float* __restrict__ w3,
                                               short* __restrict__ dst, float s0,
                                               float* __restrict__ rowsum,
                                               const float* __restrict__ bq, const float* __restrict__ bk,
                                               const float* __restrict__ bv,
                                               float* __restrict__ bqkv, float* __restrict__ statsraw) {
    int gid = blockIdx.x * 256 + threadIdx.x;
    if (gid < 8192) rowsum[gid] = 0.0f;
    if (gid < 128)  statsraw[gid] = 0.0f;
    if (gid < 1536) bqkv[gid] = (gid < 512) ? bq[gid] * s0
                               : (gid < 1024) ? bk[gid - 512] : bv[gid - 1024];
    int idx = gid * 4;
    int wi = idx >> 18;
    int off = idx & 262143;
    const float* src = (wi == 0) ? w0 : (wi == 1) ? w1 : (wi == 2) ? w2 : w3;
    float sc = (wi == 0) ? s0 : 1.0f;
    float4v v = *reinterpret_cast<const float4v*>(src + off);
    short4v o;
    o[0] = f2bf(v[0] * sc); o[1] = f2bf(v[1] * sc);
    o[2] = f2bf(v[2] * sc); o[3] = f2bf(v[3] * sc);
    *reinterpret_cast<short4v*>(dst + idx) = o;
}

// ---------------- GroupNorm partial stats: grid (64 bg, 8 chunks) ----------------
__global__ __launch_bounds__(256) void gn_stats2(const float* __restrict__ x, float* __restrict__ statsraw) {
    int bg = blockIdx.x;
    const float* p = x + (size_t)bg * 65536 + blockIdx.y * 8192;
    float s = 0.f, ss = 0.f;
    #pragma unroll
    for (int i = threadIdx.x * 4; i < 8192; i += 1024) {
        float4v q = *reinterpret_cast<const float4v*>(p + i);
        s  += q[0] + q[1] + q[2] + q[3];
        ss += q[0]*q[0] + q[1]*q[1] + q[2]*q[2] + q[3]*q[3];
    }
    #pragma unroll
    for (int off = 32; off >= 1; off >>= 1) {
        s  += __shfl_xor(s, off);
        ss += __shfl_xor(ss, off);
    }
    __shared__ float rs[8];
    int w = threadIdx.x >> 6, lane = threadIdx.x & 63;
    if (lane == 0) { rs[w] = s; rs[4 + w] = ss; }
    __syncthreads();
    if (threadIdx.x == 0) {
        float S1 = rs[0] + rs[1] + rs[2] + rs[3];
        float S2 = rs[4] + rs[5] + rs[6] + rs[7];
        atomicAdd(&statsraw[bg * 2],     S1);
        atomicAdd(&statsraw[bg * 2 + 1], S2);
    }
}

// ---------------- GN apply + transpose: x[b][c][n] -> hT[b][n][c] (bf16) ----------------
__global__ __launch_bounds__(256) void gn_apply_t(const float* __restrict__ x, const float* __restrict__ statsraw,
                                                  const float* __restrict__ scale, const float* __restrict__ bias,
                                                  short* __restrict__ hT) {
    __shared__ float t[64][65];
    int n0 = blockIdx.x * 64, c0 = blockIdx.y * 64, b = blockIdx.z;
    const float* xb = x + (size_t)b * 512 * 4096;
    int col = threadIdx.x & 63, rb = threadIdx.x >> 6;
    #pragma unroll
    for (int r = 0; r < 16; ++r) {
        int cl = rb + r * 4;
        int c = c0 + cl;
        int g = c >> 4;
        float sum   = statsraw[(b * 32 + g) * 2];
        float sumsq = statsraw[(b * 32 + g) * 2 + 1];
        float mean = sum * (1.f / 65536.f);
        float var  = sumsq * (1.f / 65536.f) - mean * mean;
        float rstd = rsqrtf(var + 1e-6f);
        float v = xb[(size_t)c * 4096 + n0 + col];
        t[col][cl] = (v - mean) * rstd * scale[c] + bias[c];
    }
    __syncthreads();
    short* hb = hT + (size_t)b * 4096 * 512;
    #pragma unroll
    for (int r = 0; r < 16; ++r) {
        int nl = rb + r * 4;
        hb[(size_t)(n0 + nl) * 512 + c0 + col] = f2bf(t[nl][col]);
    }
}

// ================ 8-phase 256x256 NT GEMM (proven structure from R13) ================
// EPI=0: plain bf16 store. EPI=1: store exp(acc); LDS-reduced rowsum, one
// atomicAdd/row/block. EPI=2: store acc * (1/rowsum[row]).
// EPI=3: QKV projection — col-bias added; cols <1024 stored to C (Q|K, ldc);
// cols >=1024 stored TRANSPOSED into vout[b][col-1024][row] (V layout [c][n]).
template<int EPI>
__global__ __launch_bounds__(512, 2) void gemm8b(
    const short* __restrict__ A, int zdiv, long sAb1, long sAb2, int lda,
    const short* __restrict__ B, long sBb1, long sBb2, int ldb,
    short* __restrict__ C, long sCb1, long sCb2, int ldc,
    int K, float* __restrict__ rowsum,
    const float* __restrict__ cbias, short* __restrict__ vout)
{
    __shared__ __align__(16) char lds[131072];

    const int tid = threadIdx.x;
    int bx = blockIdx.x, by = blockIdx.y;
    swz_xy(bx, by);
    const int bm = bx * 256, bn = by * 256;
    const int zb = blockIdx.z / zdiv, zs = blockIdx.z % zdiv;

    const short* Ab = A + (size_t)zb * sAb1 + (size_t)zs * sAb2;
    const short* Bb = B + (size_t)zb * sBb1 + (size_t)zs * sBb2;

    const int w = tid >> 6, lane = tid & 63;
    const int wm = w >> 2, wn = w & 3;
    const int l15 = lane & 15, l4 = lane >> 4;

    long srcAh[2][2], srcBh[2][2]; int dstAh[2][2], dstBh[2][2];
    #pragma unroll
    for (int h = 0; h < 2; ++h) {
        #pragma unroll
        for (int i = 0; i < 2; ++i) {
            int ch = i * 512 + tid;
            int r = h * 128 + (ch >> 3), c = ch & 7;
            srcAh[h][i] = (long)(bm + r) * lda + ((c ^ (r & 7)) << 3);
            dstAh[h][i] = r * 128 + c * 16;
            srcBh[h][i] = (long)(bn + r) * ldb + ((c ^ (r & 7)) << 3);
            dstBh[h][i] = 32768 + r * 128 + c * 16;
        }
    }
    auto stageAh = [&](int buf, int h, long kt) {
        char* l = lds + buf * 65536;
        gload_lds16(Ab + srcAh[h][0] + kt, l + dstAh[h][0]);
        gload_lds16(Ab + srcAh[h][1] + kt, l + dstAh[h][1]);
    };
    auto stageBh = [&](int buf, int h, long kt) {
        char* l = lds + buf * 65536;
        gload_lds16(Bb + srcBh[h][0] + kt, l + dstBh[h][0]);
        gload_lds16(Bb + srcBh[h][1] + kt, l + dstBh[h][1]);
    };

    auto fragA = [&](const char* base, int m, int ks) -> short8 {
        int r = wm * 128 + m * 16 + l15;
        int kk = ks * 4 + l4;
        return *reinterpret_cast<const short8*>(base + r * 128 + ((kk * 16) ^ ((r & 7) << 4)));
    };
    auto fragB = [&](const char* base, int n, int ks) -> short8 {
        int r = wn * 64 + n * 16 + l15;
        int kk = ks * 4 + l4;
        return *reinterpret_cast<const short8*>(base + 32768 + r * 128 + ((kk * 16) ^ ((r & 7) << 4)));
    };

    f32x4 acc[8][4] = {};
    const int nk = K >> 6;

    stageBh(0, 0, 0); stageBh(0, 1, 0);
    stageAh(0, 0, 0); stageAh(0, 1, 0);
    if (nk > 1) {
        stageBh(1, 0, 64); stageBh(1, 1, 64);
        wait_vm<4>();
    } else {
        wait_vm<0>();
    }
    phase_barrier();

    short8 bf[4][2];

    for (int t = 0; t < nk; ++t) {
        const char* lr = lds + (t & 1) * 65536;
        const int bufN = (t & 1) ^ 1;
        const int bufT = (t & 1);
        const long ktA = (long)(t + 1) << 6;
        const long ktB = (long)(t + 2) << 6;
        const bool pA = (t + 1 < nk);
        const bool pB = (t + 2 < nk);
        short8 a00, a01, a10, a11;

        // ---- phase 0 ----
        #pragma unroll
        for (int n = 0; n < 4; ++n) { bf[n][0] = fragB(lr, n, 0); bf[n][1] = fragB(lr, n, 1); }
        a00 = fragA(lr, 0, 0); a01 = fragA(lr, 0, 1);
        a10 = fragA(lr, 1, 0); a11 = fragA(lr, 1, 1);
        if (pA) stageAh(bufN, 0, ktA);
        wait_lgkm8();
        phase_barrier();
        wait_lgkm0();
        __builtin_amdgcn_s_setprio(1);
        #pragma unroll
        for (int n = 0; n < 4; ++n) {
            acc[0][n] = __builtin_amdgcn_mfma_f32_16x16x32_bf16(a00, bf[n][0], acc[0][n], 0, 0, 0);
            acc[0][n] = __builtin_amdgcn_mfma_f32_16x16x32_bf16(a01, bf[n][1], acc[0][n], 0, 0, 0);
            acc[1][n] = __builtin_amdgcn_mfma_f32_16x16x32_bf16(a10, bf[n][0], acc[1][n], 0, 0, 0);
            acc[1][n] = __builtin_amdgcn_mfma_f32_16x16x32_bf16(a11, bf[n][1], acc[1][n], 0, 0, 0);
        }
        __builtin_amdgcn_s_setprio(0);
        __builtin_amdgcn_sched_barrier(0);
        phase_barrier();

        // ---- phase 1 ----
        a00 = fragA(lr, 2, 0); a01 = fragA(lr, 2, 1);
        a10 = fragA(lr, 3, 0); a11 = fragA(lr, 3, 1);
        if (pA) stageAh(bufN, 1, ktA);
        phase_barrier();
        wait_lgkm0();
        __builtin_amdgcn_s_setprio(1);
        #pragma unroll
        for (int n = 0; n < 4; ++n) {
            acc[2][n] = __builtin_amdgcn_mfma_f32_16x16x32_bf16(a00, bf[n][0], acc[2][n], 0, 0, 0);
            acc[2][n] = __builtin_amdgcn_mfma_f32_16x16x32_bf16(a01, bf[n][1], acc[2][n], 0, 0, 0);
            acc[3][n] = __builtin_amdgcn_mfma_f32_16x16x32_bf16(a10, bf[n][0], acc[3][n], 0, 0, 0);
            acc[3][n] = __builtin_amdgcn_mfma_f32_16x16x32_bf16(a11, bf[n][1], acc[3][n], 0, 0, 0);
        }
        __builtin_amdgcn_s_setprio(0);
        __builtin_amdgcn_sched_barrier(0);
        phase_barrier();

        // ---- phase 2 ----
        a00 = fragA(lr, 4, 0); a01 = fragA(lr, 4, 1);
        a10 = fragA(lr, 5, 0); a11 = fragA(lr, 5, 1);
        if (pB) stageBh(bufT, 0, ktB);
        phase_barrier();
        wait_lgkm0();
        __builtin_amdgcn_s_setprio(1);
        #pragma unroll
        for (int n = 0; n < 4; ++n) {
            acc[4][n] = __builtin_amdgcn_mfma_f32_16x16x32_bf16(a00, bf[n][0], acc[4][n], 0, 0, 0);
            acc[4][n] = __builtin_amdgcn_mfma_f32_16x16x32_bf16(a01, bf[n][1], acc[4][n], 0, 0, 0);
            acc[5][n] = __builtin_amdgcn_mfma_f32_16x16x32_bf16(a10, bf[n][0], acc[5][n], 0, 0, 0);
            acc[5][n] = __builtin_amdgcn_mfma_f32_16x16x32_bf16(a11, bf[n][1], acc[5][n], 0, 0, 0);
        }
        __builtin_amdgcn_s_setprio(0);
        __builtin_amdgcn_sched_barrier(0);
        phase_barrier();

        // ---- phase 3 ----
        a00 = fragA(lr, 6, 0); a01 = fragA(lr, 6, 1);
        a10 = fragA(lr, 7, 0); a11 = fragA(lr, 7, 1);
        if (pB) stageBh(bufT, 1, ktB);
        if (pB)      wait_vm<4>();
        else if (pA) wait_vm<0>();
        phase_barrier();
        wait_lgkm0();
        __builtin_amdgcn_s_setprio(1);
        #pragma unroll
        for (int n = 0; n < 4; ++n) {
            acc[6][n] = __builtin_amdgcn_mfma_f32_16x16x32_bf16(a00, bf[n][0], acc[6][n], 0, 0, 0);
            acc[6][n] = __builtin_amdgcn_mfma_f32_16x16x32_bf16(a01, bf[n][1], acc[6][n], 0, 0, 0);
            acc[7][n] = __builtin_amdgcn_mfma_f32_16x16x32_bf16(a10, bf[n][0], acc[7][n], 0, 0, 0);
            acc[7][n] = __builtin_amdgcn_mfma_f32_16x16x32_bf16(a11, bf[n][1], acc[7][n], 0, 0, 0);
        }
        __builtin_amdgcn_s_setprio(0);
        __builtin_amdgcn_sched_barrier(0);
        phase_barrier();
    }

    short* Cb = C + (size_t)zb * sCb1 + (size_t)zs * sCb2;
    if constexpr (EPI == 0) {
        #pragma unroll
        for (int m = 0; m < 8; ++m) {
            #pragma unroll
            for (int r = 0; r < 4; ++r) {
                int row = bm + wm * 128 + m * 16 + l4 * 4 + r;
                #pragma unroll
                for (int n = 0; n < 4; ++n) {
                    int col = bn + wn * 64 + n * 16 + l15;
                    Cb[(size_t)row * ldc + col] = f2bf(acc[m][n][r]);
                }
            }
        }
    } else if constexpr (EPI == 2) {
        #pragma unroll
        for (int m = 0; m < 8; ++m) {
            #pragma unroll
            for (int r = 0; r < 4; ++r) {
                int row = bm + wm * 128 + m * 16 + l4 * 4 + r;
                float inv = 1.0f / rowsum[zb * 4096 + row];
                #pragma unroll
                for (int n = 0; n < 4; ++n) {
                    int col = bn + wn * 64 + n * 16 + l15;
                    Cb[(size_t)row * ldc + col] = f2bf(acc[m][n][r] * inv);
                }
            }
        }
    } else if constexpr (EPI == 3) {
        short* Vb = vout + (size_t)zb * (512L * 4096L);
        #pragma unroll
        for (int m = 0; m < 8; ++m) {
            #pragma unroll
            for (int r = 0; r < 4; ++r) {
                int row = bm + wm * 128 + m * 16 + l4 * 4 + r;
                #pragma unroll
                for (int n = 0; n < 4; ++n) {
                    int col = bn + wn * 64 + n * 16 + l15;
                    float v = acc[m][n][r] + cbias[col];
                    if (bn < 1024) {
                        Cb[(size_t)row * ldc + col] = f2bf(v);
                    } else {
                        Vb[(size_t)(col - 1024) * 4096 + row] = f2bf(v);
                    }
                }
            }
        }
    } else {
        float* lsum = (float*)lds;   // [wn=4][256 rows] = 4KB
        #pragma unroll
        for (int m = 0; m < 8; ++m) {
            #pragma unroll
            for (int r = 0; r < 4; ++r) {
                int lrow = wm * 128 + m * 16 + l4 * 4 + r;
                int row = bm + lrow;
                float part = 0.0f;
                #pragma unroll
                for (int n = 0; n < 4; ++n) {
                    int col = bn + wn * 64 + n * 16 + l15;
                    float e = __expf(acc[m][n][r]);
                    part += e;
                    Cb[(size_t)row * ldc + col] = f2bf(e);
                }
                part += __shfl_xor(part, 1);
                part += __shfl_xor(part, 2);
                part += __shfl_xor(part, 4);
                part += __shfl_xor(part, 8);
                if (l15 == 0) lsum[wn * 256 + lrow] = part;
            }
        }
        __syncthreads();
        if (tid < 256) {
            float s = (lsum[tid] + lsum[256 + tid]) + (lsum[512 + tid] + lsum[768 + tid]);
            atomicAdd(&rowsum[zb * 4096 + bm + tid], s);
        }
    }
}

// ================ out-projection GEMM with fused 4-way partial reduction ================
__global__ __launch_bounds__(256) void gemm_out(
    const short* __restrict__ A,
    const short* __restrict__ part, long sPz, long sPb,
    float* __restrict__ Cout, long sCb, int ldc,
    const float* __restrict__ bias,
    const float* __restrict__ res, long sResb)
{
    constexpr int BMT = 128, BNT = 64;
    constexpr int BUF = (BMT + BNT) * 128;   // 24KB
    __shared__ __align__(16) char lds[2 * BUF];

    const int tid = threadIdx.x;
    int bx = blockIdx.x, by = blockIdx.y;
    swz_xy(bx, by);
    const int bm = bx * BMT;
    const int bn = by * BNT;
    const int bz = blockIdx.z;

    const short* Pb = part + (size_t)bz * sPb;

    const int w = tid >> 6;
    const int lane = tid & 63;
    const int wr = (w >> 1) * 64;
    const int wc = (w & 1) * 32;

    f32x4 acc[4][2] = {};
    const int nk = 8;   // K=512, BK=64

    long srcA[4]; int dstA[4];
    #pragma unroll
    for (int i = 0; i < 4; ++i) {
        int ch = i * 256 + tid;
        int r = ch >> 3, c = ch & 7;
        srcA[i] = (long)(bm + r) * 512 + ((c ^ (r & 7)) << 3);
        dstA[i] = ch * 16;
    }
    long srcB[2]; int dstB[2];
    #pragma unroll
    for (int i = 0; i < 2; ++i) {
        int ch = i * 256 + tid;
        int r = ch >> 3, c = ch & 7;
        srcB[i] = (long)(bn + r) * 512 + c * 8;
        dstB[i] = BMT * 128 + r * 128 + ((c * 16) ^ ((r & 7) << 4));
    }

    auto stageA = [&](int buf, long kt) {
        char* la = lds + buf * BUF;
        #pragma unroll
        for (int i = 0; i < 4; ++i) gload_lds16(A + srcA[i] + kt, la + dstA[i]);
    };
    auto loadB = [&](long kt, short8 rv[2][4]) {
        #pragma unroll
        for (int i = 0; i < 2; ++i)
            #pragma unroll
            for (int z = 0; z < 4; ++z)
                rv[i][z] = *reinterpret_cast<const short8*>(Pb + z * sPz + srcB[i] + kt);
    };
    auto writeB = [&](int buf, short8 rv[2][4]) {
        char* l = lds + buf * BUF;
        #pragma unroll
        for (int i = 0; i < 2; ++i) {
            short8 o;
            #pragma unroll
            for (int j = 0; j < 8; ++j)
                o[j] = f2bf((bf2f(rv[i][0][j]) + bf2f(rv[i][1][j])) +
                            (bf2f(rv[i][2][j]) + bf2f(rv[i][3][j])));
            *reinterpret_cast<short8*>(l + dstB[i]) = o;
        }
    };

    short8 rv[2][4];
    stageA(0, 0);
    loadB(0, rv);
    writeB(0, rv);
    __syncthreads();

    int cur = 0;
    for (int t = 0; t < nk; ++t) {
        const bool pA = (t + 1 < nk);
        if (pA) {
            stageA(cur ^ 1, (long)(t + 1) << 6);
            loadB((long)(t + 1) << 6, rv);
        }
        const char* la = lds + cur * BUF;
        const char* lb = la + BMT * 128;
        #pragma unroll
        for (int ks = 0; ks < 2; ++ks) {
            const int kb = ks * 64 + (lane >> 4) * 16;
            short8 af[4], bfv[2];
            #pragma unroll
            for (int m = 0; m < 4; ++m) {
                int r = wr + m * 16 + (lane & 15);
                af[m] = *reinterpret_cast<const short8*>(la + r * 128 + (kb ^ ((r & 7) << 4)));
            }
            #pragma unroll
            for (int n = 0; n < 2; ++n) {
                int r = wc + n * 16 + (lane & 15);
                bfv[n] = *reinterpret_cast<const short8*>(lb + r * 128 + (kb ^ ((r & 7) << 4)));
            }
            #pragma unroll
            for (int m = 0; m < 4; ++m)
                #pragma unroll
                for (int n = 0; n < 2; ++n)
                    acc[m][n] = __builtin_amdgcn_mfma_f32_16x16x32_bf16(af[m], bfv[n], acc[m][n], 0, 0, 0);
        }
        if (pA) writeB(cur ^ 1, rv);
        __syncthreads();
        cur ^= 1;
    }

    const int row0 = (lane >> 4) * 4;
    const int col0 = lane & 15;
    float* Cb = Cout + (size_t)bz * sCb;
    const float* resb = res + (size_t)bz * sResb;

    #pragma unroll
    for (int m = 0; m < 4; ++m) {
        #pragma unroll
        for (int r = 0; r < 4; ++r) {
            int row = bm + wr + m * 16 + row0 + r;
            float bvr = bias[row];
            #pragma unroll
            for (int n = 0; n < 2; ++n) {
                int col = bn + wc + n * 16 + col0;
                size_t idx = (size_t)row * ldc + col;
                Cb[idx] = acc[m][n][r] + bvr + resb[idx];
            }
        }
    }
}

extern "C" void kernel_launch(void* const* d_in, const int* in_sizes, int n_in,
                              void* d_out, int out_size, void* d_ws, size_t ws_size,
                              hipStream_t stream) {
    (void)in_sizes; (void)n_in; (void)out_size; (void)ws_size;
    const float* x        = (const float*)d_in[0];
    const float* gn_scale = (const float*)d_in[1];
    const float* gn_bias  = (const float*)d_in[2];
    const float* wq = (const float*)d_in[3];
    const float* bq = (const float*)d_in[4];
    const float* wk = (const float*)d_in[5];
    const float* bk = (const float*)d_in[6];
    const float* wv = (const float*)d_in[7];
    const float* bv = (const float*)d_in[8];
    const float* wp = (const float*)d_in[9];
    const float* bp = (const float*)d_in[10];

    char* ws = (char*)d_ws;
    const size_t MB = 1024 * 1024;
    short* hT   = (short*)(ws + 0);         // [2][4096][512] bf16      (8MB)
    short* QKV  = (short*)(ws + 8   * MB);  // [2][4096][1536] bf16    (24MB)
    short* V    = (short*)(ws + 32  * MB);  // [2][512][4096] bf16      (8MB)
    short* S    = (short*)(ws + 40  * MB);  // [2][4096][4096] bf16    (64MB)
    short* part = (short*)(ws + 104 * MB);  // [2][4][4096][512] bf16  (32MB)
    short* wB   = (short*)(ws + 168 * MB);  // wq,wk,wv,wp bf16         (2MB)
    float* statsraw = (float*)(ws + 170 * MB);
    float* bqkv = (float*)(ws + 170 * MB + 4096);   // 1536 f
    float* rowsum = (float*)(ws + 171 * MB);        // [2][4096] fp32

    const long NC    = 4096L * 512L;
    const long CN    = 512L * 4096L;
    const long QKVN  = 4096L * 1536L;
    const long SNN   = 4096L * 4096L;
    const float attn_scale = 0.044194173824159216f;

    conv_w4<<<1024, 256, 0, stream>>>(wq, wk, wv, wp, wB, attn_scale, rowsum,
                                      bq, bk, bv, bqkv, statsraw);

    gn_stats2<<<dim3(64, 8), 256, 0, stream>>>(x, statsraw);
    gn_apply_t<<<dim3(64, 8, 2), 256, 0, stream>>>(x, statsraw, gn_scale, gn_bias, hT);

    // QKV projection (one 8-phase dispatch): QKV[b][n][0:512]=Q*s, [512:1024]=K,
    // V third written transposed into V[b][c][n]. Col bias bqkv.
    gemm8b<3><<<dim3(16, 6, 2), 512, 0, stream>>>(
        hT, 1, NC, 0, 512, wB, 0, 0, 512, QKV, QKVN, 0, 1536, 512,
        nullptr, bqkv, V);

    // S[b][i][j] = exp(QK) unnormalized; rowsum accumulated
    gemm8b<1><<<dim3(16, 16, 2), 512, 0, stream>>>(
        QKV, 1, QKVN, 0, 1536, QKV + 512, QKVN, 0, 1536, S, SNN, 0, 4096, 512,
        rowsum, nullptr, nullptr);
    // PV split-K=4, normalization folded into epilogue (EPI=2)
    gemm8b<2><<<dim3(16, 2, 8), 512, 0, stream>>>(
        S, 4, SNN, 1024, 4096, V, CN, 1024, 4096, part, 4L * NC, NC, 512, 1024,
        rowsum, nullptr, nullptr);

    // out = wp . (sum_z part[z])^T + bp + x   (reduction fused into B staging)
    gemm_out<<<dim3(4, 64, 2), 256, 0, stream>>>(
        wB + 786432, part, NC, 4L * NC, (float*)d_out, CN, 4096, bp, x, CN);
}

// Round 19
// 156.058 us; speedup vs baseline: 1.0645x; 1.0645x over previous
//
#include <hip/hip_runtime.h>
#include <stdint.h>

typedef short short8 __attribute__((ext_vector_type(8)));
typedef short short4v __attribute__((ext_vector_type(4)));
typedef float f32x4 __attribute__((ext_vector_type(4)));
typedef float float4v __attribute__((ext_vector_type(4)));

__device__ inline float bf2f(short s) {
    union { unsigned u; float f; } c;
    c.u = ((unsigned)(unsigned short)s) << 16;
    return c.f;
}
__device__ inline short f2bf(float f) {
    union { float f; unsigned u; } c;
    c.f = f;
    unsigned u = c.u;
    unsigned r = (u + 0x7fffu + ((u >> 16) & 1u)) >> 16;
    return (short)r;
}

typedef const __attribute__((address_space(1))) char GChar;
typedef __attribute__((address_space(3))) char LChar;
__device__ __forceinline__ void gload_lds16(const void* g, void* l) {
    __builtin_amdgcn_global_load_lds((GChar*)g, (LChar*)l, 16, 0, 0);
}

template<int N> __device__ __forceinline__ void wait_vm() {
    if constexpr (N == 0)      asm volatile("s_waitcnt vmcnt(0)" ::: "memory");
    else if constexpr (N == 4) asm volatile("s_waitcnt vmcnt(4)" ::: "memory");
    else if constexpr (N == 6) asm volatile("s_waitcnt vmcnt(6)" ::: "memory");
    else static_assert(N == 0 || N == 4 || N == 6, "unsupported vmcnt");
}

__device__ __forceinline__ void wait_lgkm0() {
    asm volatile("s_waitcnt lgkmcnt(0)" ::: "memory");
}
__device__ __forceinline__ void wait_lgkm8() {
    asm volatile("s_waitcnt lgkmcnt(8)" ::: "memory");
}

__device__ __forceinline__ void phase_barrier() {
    __builtin_amdgcn_s_barrier();
    asm volatile("" ::: "memory");
}

// XCD-aware (x,y)-plane swizzle; requires gridDim.x*gridDim.y % 8 == 0.
__device__ __forceinline__ void swz_xy(int& bx, int& by) {
    int gx = gridDim.x;
    int nwg = gx * gridDim.y;
    int wg = by * gx + bx;
    int chunk = nwg >> 3;
    int swz = (wg & 7) * chunk + (wg >> 3);
    bx = swz % gx;
    by = swz / gx;
}

// ------- all-4 weight fp32 -> bf16 convert (wq scaled) + bias prep + zeroing -------
__global__ __launch_bounds__(256) void conv_w4(const float* __restrict__ w0, const float* __restrict__ w1,
                                               const float* __restrict__ w2, const float* __restrict__ w3,
                                               short* __restrict__ dst, float s0,
                                               float* __restrict__ rowsum,
                                               const float* __restrict__ bq, const float* __restrict__ bk,
                                               float* __restrict__ bqk, float* __restrict__ statsraw) {
    int gid = blockIdx.x * 256 + threadIdx.x;
    if (gid < 8192) rowsum[gid] = 0.0f;
    if (gid < 128)  statsraw[gid] = 0.0f;
    if (gid < 1024) bqk[gid] = (gid < 512) ? bq[gid] * s0 : bk[gid - 512];
    int idx = gid * 4;
    int wi = idx >> 18;
    int off = idx & 262143;
    const float* src = (wi == 0) ? w0 : (wi == 1) ? w1 : (wi == 2) ? w2 : w3;
    float sc = (wi == 0) ? s0 : 1.0f;
    float4v v = *reinterpret_cast<const float4v*>(src + off);
    short4v o;
    o[0] = f2bf(v[0] * sc); o[1] = f2bf(v[1] * sc);
    o[2] = f2bf(v[2] * sc); o[3] = f2bf(v[3] * sc);
    *reinterpret_cast<short4v*>(dst + idx) = o;
}

// ---------------- GroupNorm partial stats: grid (64 bg, 8 chunks) ----------------
__global__ __launch_bounds__(256) void gn_stats2(const float* __restrict__ x, float* __restrict__ statsraw) {
    int bg = blockIdx.x;
    const float* p = x + (size_t)bg * 65536 + blockIdx.y * 8192;
    float s = 0.f, ss = 0.f;
    #pragma unroll
    for (int i = threadIdx.x * 4; i < 8192; i += 1024) {
        float4v q = *reinterpret_cast<const float4v*>(p + i);
        s  += q[0] + q[1] + q[2] + q[3];
        ss += q[0]*q[0] + q[1]*q[1] + q[2]*q[2] + q[3]*q[3];
    }
    #pragma unroll
    for (int off = 32; off >= 1; off >>= 1) {
        s  += __shfl_xor(s, off);
        ss += __shfl_xor(ss, off);
    }
    __shared__ float rs[8];
    int w = threadIdx.x >> 6, lane = threadIdx.x & 63;
    if (lane == 0) { rs[w] = s; rs[4 + w] = ss; }
    __syncthreads();
    if (threadIdx.x == 0) {
        float S1 = rs[0] + rs[1] + rs[2] + rs[3];
        float S2 = rs[4] + rs[5] + rs[6] + rs[7];
        atomicAdd(&statsraw[bg * 2],     S1);
        atomicAdd(&statsraw[bg * 2 + 1], S2);
    }
}

// ---------------- GN apply + transpose: x[b][c][n] -> hT[b][n][c] (bf16) ----------------
__global__ __launch_bounds__(256) void gn_apply_t(const float* __restrict__ x, const float* __restrict__ statsraw,
                                                  const float* __restrict__ scale, const float* __restrict__ bias,
                                                  short* __restrict__ hT) {
    __shared__ float t[64][65];
    int n0 = blockIdx.x * 64, c0 = blockIdx.y * 64, b = blockIdx.z;
    const float* xb = x + (size_t)b * 512 * 4096;
    int col = threadIdx.x & 63, rb = threadIdx.x >> 6;
    #pragma unroll
    for (int r = 0; r < 16; ++r) {
        int cl = rb + r * 4;
        int c = c0 + cl;
        int g = c >> 4;
        float sum   = statsraw[(b * 32 + g) * 2];
        float sumsq = statsraw[(b * 32 + g) * 2 + 1];
        float mean = sum * (1.f / 65536.f);
        float var  = sumsq * (1.f / 65536.f) - mean * mean;
        float rstd = rsqrtf(var + 1e-6f);
        float v = xb[(size_t)c * 4096 + n0 + col];
        t[col][cl] = (v - mean) * rstd * scale[c] + bias[c];
    }
    __syncthreads();
    short* hb = hT + (size_t)b * 4096 * 512;
    #pragma unroll
    for (int r = 0; r < 16; ++r) {
        int nl = rb + r * 4;
        hb[(size_t)(n0 + nl) * 512 + c0 + col] = f2bf(t[nl][col]);
    }
}

// ================ 8-phase 256x256 NT GEMM (proven structure from R13) ================
// EPI=0: plain bf16 store. EPI=1: store exp(acc); LDS-reduced rowsum, one
// atomicAdd/row/block. EPI=2: store acc * (1/rowsum[row]) (PV normalization).
template<int EPI>
__global__ __launch_bounds__(512, 2) void gemm8b(
    const short* __restrict__ A, int zdiv, long sAb1, long sAb2, int lda,
    const short* __restrict__ B, long sBb1, long sBb2, int ldb,
    short* __restrict__ C, long sCb1, long sCb2, int ldc,
    int K, float* __restrict__ rowsum)
{
    __shared__ __align__(16) char lds[131072];

    const int tid = threadIdx.x;
    int bx = blockIdx.x, by = blockIdx.y;
    swz_xy(bx, by);
    const int bm = bx * 256, bn = by * 256;
    const int zb = blockIdx.z / zdiv, zs = blockIdx.z % zdiv;

    const short* Ab = A + (size_t)zb * sAb1 + (size_t)zs * sAb2;
    const short* Bb = B + (size_t)zb * sBb1 + (size_t)zs * sBb2;

    const int w = tid >> 6, lane = tid & 63;
    const int wm = w >> 2, wn = w & 3;
    const int l15 = lane & 15, l4 = lane >> 4;

    long srcAh[2][2], srcBh[2][2]; int dstAh[2][2], dstBh[2][2];
    #pragma unroll
    for (int h = 0; h < 2; ++h) {
        #pragma unroll
        for (int i = 0; i < 2; ++i) {
            int ch = i * 512 + tid;
            int r = h * 128 + (ch >> 3), c = ch & 7;
            srcAh[h][i] = (long)(bm + r) * lda + ((c ^ (r & 7)) << 3);
            dstAh[h][i] = r * 128 + c * 16;
            srcBh[h][i] = (long)(bn + r) * ldb + ((c ^ (r & 7)) << 3);
            dstBh[h][i] = 32768 + r * 128 + c * 16;
        }
    }
    auto stageAh = [&](int buf, int h, long kt) {
        char* l = lds + buf * 65536;
        gload_lds16(Ab + srcAh[h][0] + kt, l + dstAh[h][0]);
        gload_lds16(Ab + srcAh[h][1] + kt, l + dstAh[h][1]);
    };
    auto stageBh = [&](int buf, int h, long kt) {
        char* l = lds + buf * 65536;
        gload_lds16(Bb + srcBh[h][0] + kt, l + dstBh[h][0]);
        gload_lds16(Bb + srcBh[h][1] + kt, l + dstBh[h][1]);
    };

    auto fragA = [&](const char* base, int m, int ks) -> short8 {
        int r = wm * 128 + m * 16 + l15;
        int kk = ks * 4 + l4;
        return *reinterpret_cast<const short8*>(base + r * 128 + ((kk * 16) ^ ((r & 7) << 4)));
    };
    auto fragB = [&](const char* base, int n, int ks) -> short8 {
        int r = wn * 64 + n * 16 + l15;
        int kk = ks * 4 + l4;
        return *reinterpret_cast<const short8*>(base + 32768 + r * 128 + ((kk * 16) ^ ((r & 7) << 4)));
    };

    f32x4 acc[8][4] = {};
    const int nk = K >> 6;

    stageBh(0, 0, 0); stageBh(0, 1, 0);
    stageAh(0, 0, 0); stageAh(0, 1, 0);
    if (nk > 1) {
        stageBh(1, 0, 64); stageBh(1, 1, 64);
        wait_vm<4>();
    } else {
        wait_vm<0>();
    }
    phase_barrier();

    short8 bf[4][2];

    for (int t = 0; t < nk; ++t) {
        const char* lr = lds + (t & 1) * 65536;
        const int bufN = (t & 1) ^ 1;
        const int bufT = (t & 1);
        const long ktA = (long)(t + 1) << 6;
        const long ktB = (long)(t + 2) << 6;
        const bool pA = (t + 1 < nk);
        const bool pB = (t + 2 < nk);
        short8 a00, a01, a10, a11;

        // ---- phase 0 ----
        #pragma unroll
        for (int n = 0; n < 4; ++n) { bf[n][0] = fragB(lr, n, 0); bf[n][1] = fragB(lr, n, 1); }
        a00 = fragA(lr, 0, 0); a01 = fragA(lr, 0, 1);
        a10 = fragA(lr, 1, 0); a11 = fragA(lr, 1, 1);
        if (pA) stageAh(bufN, 0, ktA);
        wait_lgkm8();
        phase_barrier();
        wait_lgkm0();
        __builtin_amdgcn_s_setprio(1);
        #pragma unroll
        for (int n = 0; n < 4; ++n) {
            acc[0][n] = __builtin_amdgcn_mfma_f32_16x16x32_bf16(a00, bf[n][0], acc[0][n], 0, 0, 0);
            acc[0][n] = __builtin_amdgcn_mfma_f32_16x16x32_bf16(a01, bf[n][1], acc[0][n], 0, 0, 0);
            acc[1][n] = __builtin_amdgcn_mfma_f32_16x16x32_bf16(a10, bf[n][0], acc[1][n], 0, 0, 0);
            acc[1][n] = __builtin_amdgcn_mfma_f32_16x16x32_bf16(a11, bf[n][1], acc[1][n], 0, 0, 0);
        }
        __builtin_amdgcn_s_setprio(0);
        __builtin_amdgcn_sched_barrier(0);
        phase_barrier();

        // ---- phase 1 ----
        a00 = fragA(lr, 2, 0); a01 = fragA(lr, 2, 1);
        a10 = fragA(lr, 3, 0); a11 = fragA(lr, 3, 1);
        if (pA) stageAh(bufN, 1, ktA);
        phase_barrier();
        wait_lgkm0();
        __builtin_amdgcn_s_setprio(1);
        #pragma unroll
        for (int n = 0; n < 4; ++n) {
            acc[2][n] = __builtin_amdgcn_mfma_f32_16x16x32_bf16(a00, bf[n][0], acc[2][n], 0, 0, 0);
            acc[2][n] = __builtin_amdgcn_mfma_f32_16x16x32_bf16(a01, bf[n][1], acc[2][n], 0, 0, 0);
            acc[3][n] = __builtin_amdgcn_mfma_f32_16x16x32_bf16(a10, bf[n][0], acc[3][n], 0, 0, 0);
            acc[3][n] = __builtin_amdgcn_mfma_f32_16x16x32_bf16(a11, bf[n][1], acc[3][n], 0, 0, 0);
        }
        __builtin_amdgcn_s_setprio(0);
        __builtin_amdgcn_sched_barrier(0);
        phase_barrier();

        // ---- phase 2 ----
        a00 = fragA(lr, 4, 0); a01 = fragA(lr, 4, 1);
        a10 = fragA(lr, 5, 0); a11 = fragA(lr, 5, 1);
        if (pB) stageBh(bufT, 0, ktB);
        phase_barrier();
        wait_lgkm0();
        __builtin_amdgcn_s_setprio(1);
        #pragma unroll
        for (int n = 0; n < 4; ++n) {
            acc[4][n] = __builtin_amdgcn_mfma_f32_16x16x32_bf16(a00, bf[n][0], acc[4][n], 0, 0, 0);
            acc[4][n] = __builtin_amdgcn_mfma_f32_16x16x32_bf16(a01, bf[n][1], acc[4][n], 0, 0, 0);
            acc[5][n] = __builtin_amdgcn_mfma_f32_16x16x32_bf16(a10, bf[n][0], acc[5][n], 0, 0, 0);
            acc[5][n] = __builtin_amdgcn_mfma_f32_16x16x32_bf16(a11, bf[n][1], acc[5][n], 0, 0, 0);
        }
        __builtin_amdgcn_s_setprio(0);
        __builtin_amdgcn_sched_barrier(0);
        phase_barrier();

        // ---- phase 3 ----
        a00 = fragA(lr, 6, 0); a01 = fragA(lr, 6, 1);
        a10 = fragA(lr, 7, 0); a11 = fragA(lr, 7, 1);
        if (pB) stageBh(bufT, 1, ktB);
        if (pB)      wait_vm<4>();
        else if (pA) wait_vm<0>();
        phase_barrier();
        wait_lgkm0();
        __builtin_amdgcn_s_setprio(1);
        #pragma unroll
        for (int n = 0; n < 4; ++n) {
            acc[6][n] = __builtin_amdgcn_mfma_f32_16x16x32_bf16(a00, bf[n][0], acc[6][n], 0, 0, 0);
            acc[6][n] = __builtin_amdgcn_mfma_f32_16x16x32_bf16(a01, bf[n][1], acc[6][n], 0, 0, 0);
            acc[7][n] = __builtin_amdgcn_mfma_f32_16x16x32_bf16(a10, bf[n][0], acc[7][n], 0, 0, 0);
            acc[7][n] = __builtin_amdgcn_mfma_f32_16x16x32_bf16(a11, bf[n][1], acc[7][n], 0, 0, 0);
        }
        __builtin_amdgcn_s_setprio(0);
        __builtin_amdgcn_sched_barrier(0);
        phase_barrier();
    }

    short* Cb = C + (size_t)zb * sCb1 + (size_t)zs * sCb2;
    if constexpr (EPI == 0) {
        #pragma unroll
        for (int m = 0; m < 8; ++m) {
            #pragma unroll
            for (int r = 0; r < 4; ++r) {
                int row = bm + wm * 128 + m * 16 + l4 * 4 + r;
                #pragma unroll
                for (int n = 0; n < 4; ++n) {
                    int col = bn + wn * 64 + n * 16 + l15;
                    Cb[(size_t)row * ldc + col] = f2bf(acc[m][n][r]);
                }
            }
        }
    } else if constexpr (EPI == 2) {
        #pragma unroll
        for (int m = 0; m < 8; ++m) {
            #pragma unroll
            for (int r = 0; r < 4; ++r) {
                int row = bm + wm * 128 + m * 16 + l4 * 4 + r;
                float inv = 1.0f / rowsum[zb * 4096 + row];
                #pragma unroll
                for (int n = 0; n < 4; ++n) {
                    int col = bn + wn * 64 + n * 16 + l15;
                    Cb[(size_t)row * ldc + col] = f2bf(acc[m][n][r] * inv);
                }
            }
        }
    } else {
        float* lsum = (float*)lds;   // [wn=4][256 rows] = 4KB
        #pragma unroll
        for (int m = 0; m < 8; ++m) {
            #pragma unroll
            for (int r = 0; r < 4; ++r) {
                int lrow = wm * 128 + m * 16 + l4 * 4 + r;
                int row = bm + lrow;
                float part = 0.0f;
                #pragma unroll
                for (int n = 0; n < 4; ++n) {
                    int col = bn + wn * 64 + n * 16 + l15;
                    float e = __expf(acc[m][n][r]);
                    part += e;
                    Cb[(size_t)row * ldc + col] = f2bf(e);
                }
                part += __shfl_xor(part, 1);
                part += __shfl_xor(part, 2);
                part += __shfl_xor(part, 4);
                part += __shfl_xor(part, 8);
                if (l15 == 0) lsum[wn * 256 + lrow] = part;
            }
        }
        __syncthreads();
        if (tid < 256) {
            float s = (lsum[tid] + lsum[256 + tid]) + (lsum[512 + tid] + lsum[768 + tid]);
            atomicAdd(&rowsum[zb * 4096 + bm + tid], s);
        }
    }
}

// ================ 2-phase NT GEMM (512 thr) for QK projection ================
template<int BMT, int BNT, int WM, int WN>
__global__ __launch_bounds__(512) void gemm_nt3(
    const short* __restrict__ A, int zdiv, long sAb1, long sAb2, int lda,
    const short* __restrict__ B, long sBb1, long sBb2, int ldb,
    void* __restrict__ Cv, long sCb1, long sCb2, int ldc,
    int K,
    const float* __restrict__ bias, int bias_mode,
    const float* __restrict__ res, long sResb,
    int c_fp32)
{
    constexpr int BUFB = (BMT + BNT) * 128;
    constexpr int ALPT = BMT / 64;
    constexpr int BLPT = BNT / 64;
    constexpr int MF   = BMT / WM / 16;
    constexpr int NF   = BNT / WN / 16;
    __shared__ __align__(16) char lds[2 * BUFB];

    const int tid = threadIdx.x;
    int bx = blockIdx.x, by = blockIdx.y;
    swz_xy(bx, by);
    const int bm = bx * BMT;
    const int bn = by * BNT;
    const int bz = blockIdx.z;
    const int zb = bz / zdiv, zs = bz % zdiv;

    const short* Ab = A + (size_t)zb * sAb1 + (size_t)zs * sAb2;
    const short* Bb = B + (size_t)zb * sBb1 + (size_t)zs * sBb2;

    const int w = tid >> 6;
    const int lane = tid & 63;
    const int wm = w / WN, wn = w % WN;
    const int wr = wm * (BMT / WM);
    const int wc = wn * (BNT / WN);

    f32x4 acc[MF][NF] = {};
    const int nk = K >> 6;

    auto stage = [&](int buf, int kt) {
        char* la = lds + buf * BUFB;
        char* lb = la + BMT * 128;
        #pragma unroll
        for (int i = 0; i < ALPT; ++i) {
            int ch = i * 512 + tid;
            int r = ch >> 3, c = ch & 7;
            gload_lds16(Ab + (size_t)(bm + r) * lda + kt + ((c ^ (r & 7)) << 3), la + ch * 16);
        }
        #pragma unroll
        for (int i = 0; i < BLPT; ++i) {
            int ch = i * 512 + tid;
            int r = ch >> 3, c = ch & 7;
            gload_lds16(Bb + (size_t)(bn + r) * ldb + kt + ((c ^ (r & 7)) << 3), lb + ch * 16);
        }
    };

    stage(0, 0);
    int cur = 0;
    for (int t = 0; t < nk; ++t) {
        if (t + 1 < nk) {
            stage(cur ^ 1, (t + 1) << 6);
            wait_vm<6>();
        } else {
            wait_vm<0>();
        }
        phase_barrier();

        const char* la = lds + cur * BUFB;
        const char* lb = la + BMT * 128;
        #pragma unroll
        for (int ks = 0; ks < 2; ++ks) {
            const int kb = ks * 64 + (lane >> 4) * 16;
            short8 af[MF], bfv[NF];
            #pragma unroll
            for (int m = 0; m < MF; ++m) {
                int r = wr + m * 16 + (lane & 15);
                af[m] = *reinterpret_cast<const short8*>(la + r * 128 + (kb ^ ((r & 7) << 4)));
            }
            #pragma unroll
            for (int n = 0; n < NF; ++n) {
                int r = wc + n * 16 + (lane & 15);
                bfv[n] = *reinterpret_cast<const short8*>(lb + r * 128 + (kb ^ ((r & 7) << 4)));
            }
            #pragma unroll
            for (int m = 0; m < MF; ++m)
                #pragma unroll
                for (int n = 0; n < NF; ++n)
                    acc[m][n] = __builtin_amdgcn_mfma_f32_16x16x32_bf16(af[m], bfv[n], acc[m][n], 0, 0, 0);
        }
        asm volatile("" ::: "memory");
        __builtin_amdgcn_s_barrier();
        cur ^= 1;
    }

    const int row0 = (lane >> 4) * 4;
    const int col0 = lane & 15;
    short* Cb16 = (short*)Cv + (size_t)zb * sCb1 + (size_t)zs * sCb2;
    float* Cf32 = (float*)Cv + (size_t)zb * sCb1 + (size_t)zs * sCb2;
    const float* resb = res ? res + (size_t)zb * sResb : nullptr;

    #pragma unroll
    for (int m = 0; m < MF; ++m) {
        #pragma unroll
        for (int r = 0; r < 4; ++r) {
            int row = bm + wr + m * 16 + row0 + r;
            float bvr = (bias_mode == 1) ? bias[row] : 0.0f;
            #pragma unroll
            for (int n = 0; n < NF; ++n) {
                int col = bn + wc + n * 16 + col0;
                float v = acc[m][n][r];
                if (bias_mode == 1) v += bvr;
                else if (bias_mode == 2) v += bias[col];
                size_t idx = (size_t)row * ldc + col;
                if (c_fp32) {
                    if (resb) v += resb[idx];
                    Cf32[idx] = v;
                } else {
                    Cb16[idx] = f2bf(v);
                }
            }
        }
    }
}

// ---------------- small NT GEMM (4 waves, 128 x BNT), counted-vmcnt pipeline ----------------
template<int BNT>
__global__ __launch_bounds__(256) void gemm_nt2(
    const short* __restrict__ A, long sAb, int lda,
    const short* __restrict__ B, long sBb, int ldb,
    void* __restrict__ Cv, long sCb, int ldc,
    int K,
    const float* __restrict__ bias, int bias_mode,
    const float* __restrict__ res, long sResb,
    int c_fp32)
{
    constexpr int BMT = 128;
    constexpr int NF  = BNT / 32;
    constexpr int BUF = (BMT + BNT) * 128;
    constexpr int ALPT = (BMT * 8) / 256;
    constexpr int BLPT = (BNT * 8) / 256;
    __shared__ __align__(16) char lds[2 * BUF];

    const int tid = threadIdx.x;
    int bx = blockIdx.x, by = blockIdx.y;
    swz_xy(bx, by);
    const int bm = bx * BMT;
    const int bn = by * BNT;
    const int bz = blockIdx.z;

    const short* Ab = A + (size_t)bz * sAb;
    const short* Bb = B + (size_t)bz * sBb;

    const int w = tid >> 6;
    const int lane = tid & 63;
    const int wr = (w >> 1) * 64;
    const int wc = (w & 1) * (BNT / 2);

    f32x4 acc[4][NF] = {};
    const int nk = K >> 6;

    auto stage = [&](int buf, int kt) {
        char* la = lds + buf * BUF;
        char* lb = la + BMT * 128;
        #pragma unroll
        for (int i = 0; i < ALPT; ++i) {
            int ch = i * 256 + tid;
            int r = ch >> 3, c = ch & 7;
            gload_lds16(Ab + (size_t)(bm + r) * lda + kt + ((c ^ (r & 7)) << 3), la + ch * 16);
        }
        #pragma unroll
        for (int i = 0; i < BLPT; ++i) {
            int ch = i * 256 + tid;
            int r = ch >> 3, c = ch & 7;
            gload_lds16(Bb + (size_t)(bn + r) * ldb + kt + ((c ^ (r & 7)) << 3), lb + ch * 16);
        }
    };

    stage(0, 0);
    int cur = 0;
    for (int t = 0; t < nk; ++t) {
        if (t + 1 < nk) {
            stage(cur ^ 1, (t + 1) << 6);
            wait_vm<6>();
        } else {
            wait_vm<0>();
        }
        phase_barrier();

        const char* la = lds + cur * BUF;
        const char* lb = la + BMT * 128;
        #pragma unroll
        for (int ks = 0; ks < 2; ++ks) {
            const int kb = ks * 64 + (lane >> 4) * 16;
            short8 af[4], bfv[NF];
            #pragma unroll
            for (int m = 0; m < 4; ++m) {
                int r = wr + m * 16 + (lane & 15);
                af[m] = *reinterpret_cast<const short8*>(la + r * 128 + (kb ^ ((r & 7) << 4)));
            }
            #pragma unroll
            for (int n = 0; n < NF; ++n) {
                int r = wc + n * 16 + (lane & 15);
                bfv[n] = *reinterpret_cast<const short8*>(lb + r * 128 + (kb ^ ((r & 7) << 4)));
            }
            #pragma unroll
            for (int m = 0; m < 4; ++m)
                #pragma unroll
                for (int n = 0; n < NF; ++n)
                    acc[m][n] = __builtin_amdgcn_mfma_f32_16x16x32_bf16(af[m], bfv[n], acc[m][n], 0, 0, 0);
        }
        asm volatile("" ::: "memory");
        __builtin_amdgcn_s_barrier();
        cur ^= 1;
    }

    const int row0 = (lane >> 4) * 4;
    const int col0 = lane & 15;
    short* Cb16 = (short*)Cv + (size_t)bz * sCb;
    float* Cf32 = (float*)Cv + (size_t)bz * sCb;
    const float* resb = res ? res + (size_t)bz * sResb : nullptr;

    #pragma unroll
    for (int m = 0; m < 4; ++m) {
        #pragma unroll
        for (int r = 0; r < 4; ++r) {
            int row = bm + wr + m * 16 + row0 + r;
            float bvr = (bias_mode == 1) ? bias[row] : 0.0f;
            #pragma unroll
            for (int n = 0; n < NF; ++n) {
                int col = bn + wc + n * 16 + col0;
                float v = acc[m][n][r];
                if (bias_mode == 1) v += bvr;
                else if (bias_mode == 2) v += bias[col];
                size_t idx = (size_t)row * ldc + col;
                if (c_fp32) {
                    if (resb) v += resb[idx];
                    Cf32[idx] = v;
                } else {
                    Cb16[idx] = f2bf(v);
                }
            }
        }
    }
}

// ================ out-projection GEMM with fused 4-way partial reduction ================
__global__ __launch_bounds__(256) void gemm_out(
    const short* __restrict__ A,
    const short* __restrict__ part, long sPz, long sPb,
    float* __restrict__ Cout, long sCb, int ldc,
    const float* __restrict__ bias,
    const float* __restrict__ res, long sResb)
{
    constexpr int BMT = 128, BNT = 64;
    constexpr int BUF = (BMT + BNT) * 128;   // 24KB
    __shared__ __align__(16) char lds[2 * BUF];

    const int tid = threadIdx.x;
    int bx = blockIdx.x, by = blockIdx.y;
    swz_xy(bx, by);
    const int bm = bx * BMT;
    const int bn = by * BNT;
    const int bz = blockIdx.z;

    const short* Pb = part + (size_t)bz * sPb;

    const int w = tid >> 6;
    const int lane = tid & 63;
    const int wr = (w >> 1) * 64;
    const int wc = (w & 1) * 32;

    f32x4 acc[4][2] = {};
    const int nk = 8;   // K=512, BK=64

    long srcA[4]; int dstA[4];
    #pragma unroll
    for (int i = 0; i < 4; ++i) {
        int ch = i * 256 + tid;
        int r = ch >> 3, c = ch & 7;
        srcA[i] = (long)(bm + r) * 512 + ((c ^ (r & 7)) << 3);
        dstA[i] = ch * 16;
    }
    long srcB[2]; int dstB[2];
    #pragma unroll
    for (int i = 0; i < 2; ++i) {
        int ch = i * 256 + tid;
        int r = ch >> 3, c = ch & 7;
        srcB[i] = (long)(bn + r) * 512 + c * 8;
        dstB[i] = BMT * 128 + r * 128 + ((c * 16) ^ ((r & 7) << 4));
    }

    auto stageA = [&](int buf, long kt) {
        char* la = lds + buf * BUF;
        #pragma unroll
        for (int i = 0; i < 4; ++i) gload_lds16(A + srcA[i] + kt, la + dstA[i]);
    };
    auto loadB = [&](long kt, short8 rv[2][4]) {
        #pragma unroll
        for (int i = 0; i < 2; ++i)
            #pragma unroll
            for (int z = 0; z < 4; ++z)
                rv[i][z] = *reinterpret_cast<const short8*>(Pb + z * sPz + srcB[i] + kt);
    };
    auto writeB = [&](int buf, short8 rv[2][4]) {
        char* l = lds + buf * BUF;
        #pragma unroll
        for (int i = 0; i < 2; ++i) {
            short8 o;
            #pragma unroll
            for (int j = 0; j < 8; ++j)
                o[j] = f2bf((bf2f(rv[i][0][j]) + bf2f(rv[i][1][j])) +
                            (bf2f(rv[i][2][j]) + bf2f(rv[i][3][j])));
            *reinterpret_cast<short8*>(l + dstB[i]) = o;
        }
    };

    short8 rv[2][4];
    stageA(0, 0);
    loadB(0, rv);
    writeB(0, rv);
    __syncthreads();

    int cur = 0;
    for (int t = 0; t < nk; ++t) {
        const bool pA = (t + 1 < nk);
        if (pA) {
            stageA(cur ^ 1, (long)(t + 1) << 6);
            loadB((long)(t + 1) << 6, rv);
        }
        const char* la = lds + cur * BUF;
        const char* lb = la + BMT * 128;
        #pragma unroll
        for (int ks = 0; ks < 2; ++ks) {
            const int kb = ks * 64 + (lane >> 4) * 16;
            short8 af[4], bfv[2];
            #pragma unroll
            for (int m = 0; m < 4; ++m) {
                int r = wr + m * 16 + (lane & 15);
                af[m] = *reinterpret_cast<const short8*>(la + r * 128 + (kb ^ ((r & 7) << 4)));
            }
            #pragma unroll
            for (int n = 0; n < 2; ++n) {
                int r = wc + n * 16 + (lane & 15);
                bfv[n] = *reinterpret_cast<const short8*>(lb + r * 128 + (kb ^ ((r & 7) << 4)));
            }
            #pragma unroll
            for (int m = 0; m < 4; ++m)
                #pragma unroll
                for (int n = 0; n < 2; ++n)
                    acc[m][n] = __builtin_amdgcn_mfma_f32_16x16x32_bf16(af[m], bfv[n], acc[m][n], 0, 0, 0);
        }
        if (pA) writeB(cur ^ 1, rv);
        __syncthreads();
        cur ^= 1;
    }

    const int row0 = (lane >> 4) * 4;
    const int col0 = lane & 15;
    float* Cb = Cout + (size_t)bz * sCb;
    const float* resb = res + (size_t)bz * sResb;

    #pragma unroll
    for (int m = 0; m < 4; ++m) {
        #pragma unroll
        for (int r = 0; r < 4; ++r) {
            int row = bm + wr + m * 16 + row0 + r;
            float bvr = bias[row];
            #pragma unroll
            for (int n = 0; n < 2; ++n) {
                int col = bn + wc + n * 16 + col0;
                size_t idx = (size_t)row * ldc + col;
                Cb[idx] = acc[m][n][r] + bvr + resb[idx];
            }
        }
    }
}

extern "C" void kernel_launch(void* const* d_in, const int* in_sizes, int n_in,
                              void* d_out, int out_size, void* d_ws, size_t ws_size,
                              hipStream_t stream) {
    (void)in_sizes; (void)n_in; (void)out_size; (void)ws_size;
    const float* x        = (const float*)d_in[0];
    const float* gn_scale = (const float*)d_in[1];
    const float* gn_bias  = (const float*)d_in[2];
    const float* wq = (const float*)d_in[3];
    const float* bq = (const float*)d_in[4];
    const float* wk = (const float*)d_in[5];
    const float* bk = (const float*)d_in[6];
    const float* wv = (const float*)d_in[7];
    const float* bv = (const float*)d_in[8];
    const float* wp = (const float*)d_in[9];
    const float* bp = (const float*)d_in[10];

    char* ws = (char*)d_ws;
    const size_t MB = 1024 * 1024;
    short* hT   = (short*)(ws + 0);
    short* QKT  = (short*)(ws + 8   * MB);
    short* V    = (short*)(ws + 24  * MB);
    short* S    = (short*)(ws + 40  * MB);
    short* part = (short*)(ws + 104 * MB);
    short* wB   = (short*)(ws + 168 * MB);
    float* statsraw = (float*)(ws + 170 * MB);
    float* bqk  = (float*)(ws + 170 * MB + 4096);
    float* rowsum = (float*)(ws + 171 * MB);   // [2][4096] fp32

    const long NC   = 4096L * 512L;
    const long CN   = 512L * 4096L;
    const long QKNC = 4096L * 1024L;
    const long SNN  = 4096L * 4096L;
    const float attn_scale = 0.044194173824159216f;

    conv_w4<<<1024, 256, 0, stream>>>(wq, wk, wv, wp, wB, attn_scale, rowsum,
                                      bq, bk, bqk, statsraw);

    gn_stats2<<<dim3(64, 8), 256, 0, stream>>>(x, statsraw);
    gn_apply_t<<<dim3(64, 8, 2), 256, 0, stream>>>(x, statsraw, gn_scale, gn_bias, hT);

    // QK projection (merged): QKT[b][n][0:512]=Q*s, [512:1024]=K
    gemm_nt3<128, 256, 2, 4><<<dim3(32, 4, 2), 512, 0, stream>>>(
        hT, 1, NC, 0, 512, wB, 0, 0, 512, QKT, QKNC, 0, 1024, 512, bqk, 2, nullptr, 0, 0);
    // V[b][c][n]
    gemm_nt2<64><<<dim3(4, 64, 2), 256, 0, stream>>>(
        wB + 524288, 0, 512, hT, NC, 512, V, CN, 4096, 512, bv, 1, nullptr, 0, 0);

    // S[b][i][j] = exp(QK) unnormalized; rowsum accumulated
    gemm8b<1><<<dim3(16, 16, 2), 512, 0, stream>>>(
        QKT, 1, QKNC, 0, 1024, QKT + 512, QKNC, 0, 1024, S, SNN, 0, 4096, 512, rowsum);
    // PV split-K=4, normalization folded into epilogue (EPI=2)
    gemm8b<2><<<dim3(16, 2, 8), 512, 0, stream>>>(
        S, 4, SNN, 1024, 4096, V, CN, 1024, 4096, part, 4L * NC, NC, 512, 1024, rowsum);

    // out = wp . (sum_z part[z])^T + bp + x   (reduction fused into B staging)
    gemm_out<<<dim3(4, 64, 2), 256, 0, stream>>>(
        wB + 786432, part, NC, 4L * NC, (float*)d_out, CN, 4096, bp, x, CN);
}